// Round 3
// baseline (3069.079 us; speedup 1.0000x reference)
//
#include <hip/hip_runtime.h>

#define TSTEPS 8192
#define NSEG   2048
#define DTC    0.025f

// Persistent single-wave halo decomposition: 256 blocks x 64 lanes, one per CU.
// Each block owns COWN=8 segments; each phase advances KST=28 steps using a
// 28-lane halo per side (validity cone shrinks 1 lane/side/step). Between
// phases: publish owned state to a double-buffered global array + flag
// (release, agent scope); spin on the 9 neighbor flags (acquire). No kernel
// relaunch, no grid-wide barrier.
#define KST    28
#define WAVE   64
#define COWN   (WAVE - 2 * KST)                 // 8
#define NBLK   (NSEG / COWN)                    // 256
#define NPHASE ((TSTEPS + KST - 1) / KST)       // 293 (last phase = 16 steps)
#define FSTR   16                               // flag stride in ints (64B)

constexpr double L2E = 1.4426950408889634074;   // log2(e)

#define AM_A ((float)(-0.1 * L2E))              // em0 = exp2(AM_A*V) = e^{-0.1V}
#define CEM  0.018315638888734179f              // e^-4    -> am's exp
#define CEH  0.030197383422318501f              // e^-3.5  -> bh's exp
#define CEN  0.0040867714384640666f             // e^-5.5  -> an's exp
#define BM_A ((float)(-L2E / 18.0))
#define BM_B ((float)(2.0 - 65.0 * L2E / 18.0)) // bm = exp2(BM_A*V+BM_B) = 4e^{-(V+65)/18}
#define QA   ((float)(-L2E / 80.0))
#define QB   ((float)(-65.0 * L2E / 80.0))      // q = e^{-(V+65)/80}; bn=q/8; ah=0.07q^4
#define CAH  0.2645751311064591f                // sqrt(0.07)

__device__ __forceinline__ void hh_step(
    float& V, float& m, float& h, float& n, float is,
    bool le, bool re, float gna, float gk, float gl, float gax,
    float& mem_cur, float& Vpre)
{
    // shuffles first: ds latency overlaps the rate math below
    float Vl = __shfl_up(V, 1);
    float Vr = __shfl_down(V, 1);
    Vl = le ? V : Vl;
    Vr = re ? V : Vr;

    // 3 exp2 + 3 rcp per step (shared e^{-0.1V}; ah via q^4)
    const float em0 = __builtin_amdgcn_exp2f(V * AM_A);
    const float am  = __builtin_fmaf(0.1f, V, 4.0f) *
                      __builtin_amdgcn_rcpf(__builtin_fmaf(-CEM, em0, 1.0f));
    const float bh  = __builtin_amdgcn_rcpf(__builtin_fmaf(CEH, em0, 1.0f));
    const float an  = __builtin_fmaf(0.01f, V, 0.55f) *
                      __builtin_amdgcn_rcpf(__builtin_fmaf(-CEN, em0, 1.0f));
    const float bm  = __builtin_amdgcn_exp2f(__builtin_fmaf(V, BM_A, BM_B));
    const float q   = __builtin_amdgcn_exp2f(__builtin_fmaf(V, QA, QB));
    const float q2  = q * q;
    const float tq  = CAH * q2;
    const float ah  = tq * tq;                  // 0.07 * q^4
    const float bn  = 0.125f * q;

    const float m3 = m * m * m;
    const float n2 = n * n;
    const float n4 = n2 * n2;
    const float i_ion = gna * m3 * h * (V - 50.0f)
                      + gk * n4 * (V + 77.0f)
                      + gl * (V + 54.387f);
    const float ax = (Vl + Vr) - 2.0f * V;
    const float dV = __builtin_fmaf(gax, ax, is - i_ion);   // CM = 1

    mem_cur = dV + i_ion;
    Vpre = V;

    V = __builtin_fmaf(DTC, dV, V);
    m = __builtin_fmaf(DTC, __builtin_fmaf(-(am + bm), m, am), m);
    h = __builtin_fmaf(DTC, __builtin_fmaf(-(ah + bh), h, ah), h);
    n = __builtin_fmaf(DTC, __builtin_fmaf(-(an + bn), n, an), n);
}

__global__ __launch_bounds__(WAVE, 1) void hh_persist(
    const float* __restrict__ stim,
    const float* __restrict__ gna_p, const float* __restrict__ gk_p,
    const float* __restrict__ gl_p,  const float* __restrict__ gax_p,
    float* __restrict__ bufs,        // 2 buffers x 4*NSEG floats (V,m,h,n)
    int*   __restrict__ flags,       // NBLK * FSTR ints
    float* __restrict__ out_cur, float* __restrict__ out_volt,
    float* __restrict__ tail)
{
    const int j = threadIdx.x;
    const int b = blockIdx.x;
    const int s = b * COWN - KST + j;               // may be out of range (halo)
    const int sc = s < 0 ? 0 : (s > NSEG - 1 ? NSEG - 1 : s);
    const bool owned = (j >= KST) && (j < KST + COWN);
    const bool le = (s <= 0);                        // sealed end: neighbor = self
    const bool re = (s >= NSEG - 1);

    const float gna = gna_p[sc], gk = gk_p[sc], gl = gl_p[sc], gax = gax_p[sc];

    // halo [8b-28, 8b+36) spans blocks b-4..b+4; lanes 0..8 spin one flag each
    int nbb = b - 4 + j;
    if (j >= 9) nbb = b;
    nbb = nbb < 0 ? 0 : (nbb > NBLK - 1 ? NBLK - 1 : nbb);
    const int* flagp = flags + nbb * FSTR;

    for (int p = 0; p < NPHASE; ++p) {
        const int t0 = p * KST;
        const int ks = (TSTEPS - t0) < KST ? (TSTEPS - t0) : KST;
        const float* sp = stim + (size_t)t0 * NSEG + sc;

        // issue this phase's stim loads BEFORE the spin: spin covers HBM latency
        float st[KST];
        if (ks == KST) {
#pragma unroll
            for (int k = 0; k < KST; ++k)
                st[k] = sp[(size_t)k * NSEG];
        }

        if (p) {
            int got;
            do {
                got = __hip_atomic_load(flagp, __ATOMIC_RELAXED,
                                        __HIP_MEMORY_SCOPE_AGENT);
            } while (!__all(got >= p));
            __builtin_amdgcn_fence(__ATOMIC_ACQUIRE, "agent");
        }

        // publication of phase p-1 lives in buf[(p-1)&1] == buf[(p+1)&1]
        const float* sb = bufs + (size_t)((p + 1) & 1) * 4 * NSEG;
        float V = sb[sc];
        float m = sb[NSEG + sc];
        float h = sb[2 * NSEG + sc];
        float n = sb[3 * NSEG + sc];

        float* oc = out_cur  + (size_t)t0 * NSEG + s;   // used only when owned
        float* ov = out_volt + (size_t)t0 * NSEG + s;

        if (ks == KST) {
#pragma unroll
            for (int k = 0; k < KST; ++k) {
                float mc, vp;
                hh_step(V, m, h, n, st[k], le, re, gna, gk, gl, gax, mc, vp);
                if (owned) {
                    __builtin_nontemporal_store(mc, oc + (size_t)k * NSEG);
                    __builtin_nontemporal_store(vp, ov + (size_t)k * NSEG);
                }
            }
        } else {
#pragma unroll 4
            for (int k = 0; k < ks; ++k) {
                float mc, vp;
                hh_step(V, m, h, n, sp[(size_t)k * NSEG], le, re,
                        gna, gk, gl, gax, mc, vp);
                if (owned) {
                    __builtin_nontemporal_store(mc, oc + (size_t)k * NSEG);
                    __builtin_nontemporal_store(vp, ov + (size_t)k * NSEG);
                }
            }
        }

        if (p + 1 < NPHASE) {
            float* pb = bufs + (size_t)(p & 1) * 4 * NSEG;
            if (owned) {
                pb[s] = V; pb[NSEG + s] = m; pb[2*NSEG + s] = h; pb[3*NSEG + s] = n;
            }
            __builtin_amdgcn_fence(__ATOMIC_RELEASE, "agent");
            if (j == 0)
                __hip_atomic_store(flags + b * FSTR, p + 1,
                                   __ATOMIC_RELAXED, __HIP_MEMORY_SCOPE_AGENT);
        } else if (owned) {
            tail[s] = V; tail[NSEG + s] = m;
            tail[2 * NSEG + s] = h; tail[3 * NSEG + s] = n;
        }
    }
}

__global__ void hh_init(const float* __restrict__ V0, const float* __restrict__ m0,
                        const float* __restrict__ h0, const float* __restrict__ n0,
                        float* __restrict__ bufs, int* __restrict__ flags)
{
    const int i = blockIdx.x * blockDim.x + threadIdx.x;
    if (i < NSEG) {
        float* b1 = bufs + 4 * NSEG;       // initial state = "publication of phase -1" -> buf1
        b1[i]            = V0[i];
        b1[NSEG + i]     = m0[i];
        b1[2 * NSEG + i] = h0[i];
        b1[3 * NSEG + i] = n0[i];
    }
    if (i < NBLK * FSTR) flags[i] = 0;     // reset every launch (deterministic replay)
}

extern "C" void kernel_launch(void* const* d_in, const int* in_sizes, int n_in,
                              void* d_out, int out_size, void* d_ws, size_t ws_size,
                              hipStream_t stream)
{
    const float* stim = (const float*)d_in[0];
    const float* V0   = (const float*)d_in[1];
    const float* m0   = (const float*)d_in[2];
    const float* h0   = (const float*)d_in[3];
    const float* n0   = (const float*)d_in[4];
    const float* gna  = (const float*)d_in[5];
    const float* gk   = (const float*)d_in[6];
    const float* gl   = (const float*)d_in[7];
    const float* gax  = (const float*)d_in[8];

    float* out      = (float*)d_out;
    float* out_cur  = out;
    float* out_volt = out + (size_t)TSTEPS * NSEG;
    float* tail     = out + 2 * (size_t)TSTEPS * NSEG;   // Vf, mf, hf, nf

    float* bufs = (float*)d_ws;                                   // 2 * 4*NSEG floats
    int*   flags = (int*)((char*)d_ws + (size_t)8 * NSEG * sizeof(float));

    hipLaunchKernelGGL(hh_init, dim3(16), dim3(256), 0, stream,
                       V0, m0, h0, n0, bufs, flags);
    hipLaunchKernelGGL(hh_persist, dim3(NBLK), dim3(WAVE), 0, stream,
                       stim, gna, gk, gl, gax, bufs, flags,
                       out_cur, out_volt, tail);
}

// Round 4
// 1457.678 us; speedup vs baseline: 2.1055x; 2.1055x over previous
//
#include <hip/hip_runtime.h>

typedef unsigned long long u64;
typedef unsigned int u32;

#define TSTEPS 8192
#define NSEG   2048
#define DTC    0.025f

// Persistent single-wave halo decomposition: 256 blocks x 64 lanes (1/CU).
// Each block owns COWN=8 segments; each phase advances KST=28 steps with a
// 28-lane halo per side. Inter-block sync is FENCE-FREE: state is published
// as (tag<<32 | f32bits) 8-byte relaxed agent-scope atomics (performed at the
// coherence point, bypassing the non-coherent per-XCD L2), and readers spin
// on their own 4 tagged words. Value and tag travel in one atomic word, so
// no acquire/release fence (and no L2 invalidation) is needed.
#define KST    28
#define WAVE   64
#define COWN   (WAVE - 2 * KST)                 // 8
#define NBLK   (NSEG / COWN)                    // 256
#define NPHASE ((TSTEPS + KST - 1) / KST)       // 293 (last phase = 16 steps)

constexpr double L2E = 1.4426950408889634074;   // log2(e)

#define AM_A ((float)(-0.1 * L2E))              // em0 = exp2(AM_A*V) = e^{-0.1V}
#define CEM  0.018315638888734179f              // e^-4    -> am's exp
#define CEH  0.030197383422318501f              // e^-3.5  -> bh's exp
#define CEN  0.0040867714384640666f             // e^-5.5  -> an's exp
#define BM_A ((float)(-L2E / 18.0))
#define BM_B ((float)(2.0 - 65.0 * L2E / 18.0)) // bm = 4e^{-(V+65)/18}
#define QA   ((float)(-L2E / 80.0))
#define QB   ((float)(-65.0 * L2E / 80.0))      // q = e^{-(V+65)/80}; bn=q/8; ah=0.07q^4
#define CAH  0.2645751311064591f                // sqrt(0.07)

__device__ __forceinline__ void hh_step(
    float& V, float& m, float& h, float& n, float is,
    bool le, bool re, float gna, float gk, float gl, float gax,
    float& mem_cur, float& Vpre)
{
    // shuffles first: ds latency overlaps the rate math below
    float Vl = __shfl_up(V, 1);
    float Vr = __shfl_down(V, 1);
    Vl = le ? V : Vl;
    Vr = re ? V : Vr;

    // 3 exp2 + 3 rcp per step (shared e^{-0.1V}; ah via q^4)
    const float em0 = __builtin_amdgcn_exp2f(V * AM_A);
    const float am  = __builtin_fmaf(0.1f, V, 4.0f) *
                      __builtin_amdgcn_rcpf(__builtin_fmaf(-CEM, em0, 1.0f));
    const float bh  = __builtin_amdgcn_rcpf(__builtin_fmaf(CEH, em0, 1.0f));
    const float an  = __builtin_fmaf(0.01f, V, 0.55f) *
                      __builtin_amdgcn_rcpf(__builtin_fmaf(-CEN, em0, 1.0f));
    const float bm  = __builtin_amdgcn_exp2f(__builtin_fmaf(V, BM_A, BM_B));
    const float q   = __builtin_amdgcn_exp2f(__builtin_fmaf(V, QA, QB));
    const float q2  = q * q;
    const float tq  = CAH * q2;
    const float ah  = tq * tq;                  // 0.07 * q^4
    const float bn  = 0.125f * q;

    const float m3 = m * m * m;
    const float n2 = n * n;
    const float n4 = n2 * n2;
    const float i_ion = gna * m3 * h * (V - 50.0f)
                      + gk * n4 * (V + 77.0f)
                      + gl * (V + 54.387f);
    const float ax = (Vl + Vr) - 2.0f * V;
    const float dV = __builtin_fmaf(gax, ax, is - i_ion);   // CM = 1

    mem_cur = dV + i_ion;
    Vpre = V;

    V = __builtin_fmaf(DTC, dV, V);
    m = __builtin_fmaf(DTC, __builtin_fmaf(-(am + bm), m, am), m);
    h = __builtin_fmaf(DTC, __builtin_fmaf(-(ah + bh), h, ah), h);
    n = __builtin_fmaf(DTC, __builtin_fmaf(-(an + bn), n, an), n);
}

__device__ __forceinline__ u64 pack_tag(float v, int tag)
{
    return ((u64)(u32)tag << 32) | (u64)__float_as_uint(v);
}

__global__ __launch_bounds__(WAVE, 1) void hh_persist(
    const float* __restrict__ stim,
    const float* __restrict__ gna_p, const float* __restrict__ gk_p,
    const float* __restrict__ gl_p,  const float* __restrict__ gax_p,
    u64* __restrict__ tstate,        // 2 buffers x 4 comps x NSEG tagged words
    float* __restrict__ out_cur, float* __restrict__ out_volt,
    float* __restrict__ tail)
{
    const int j = threadIdx.x;
    const int b = blockIdx.x;
    const int s = b * COWN - KST + j;               // may be out of range (halo)
    const int sc = s < 0 ? 0 : (s > NSEG - 1 ? NSEG - 1 : s);
    const bool owned = (j >= KST) && (j < KST + COWN);
    const bool le = (s <= 0);                        // sealed end: neighbor = self
    const bool re = (s >= NSEG - 1);

    const float gna = gna_p[sc], gk = gk_p[sc], gl = gl_p[sc], gax = gax_p[sc];

    for (int p = 0; p < NPHASE; ++p) {
        const int t0 = p * KST;
        const int ks = (TSTEPS - t0) < KST ? (TSTEPS - t0) : KST;
        const float* sp = stim + (size_t)t0 * NSEG + sc;

        // issue this phase's stim loads BEFORE the spin: spin covers HBM latency
        float st[KST];
        if (ks == KST) {
#pragma unroll
            for (int k = 0; k < KST; ++k)
                st[k] = sp[(size_t)k * NSEG];
        }

        // spin on own 4 tagged words; value rides in the same atomic word
        const u64* sb = tstate + (size_t)(p & 1) * 4 * NSEG;
        u64 w0, w1, w2, w3;
        do {
            w0 = __hip_atomic_load(sb + sc,            __ATOMIC_RELAXED, __HIP_MEMORY_SCOPE_AGENT);
            w1 = __hip_atomic_load(sb + NSEG + sc,     __ATOMIC_RELAXED, __HIP_MEMORY_SCOPE_AGENT);
            w2 = __hip_atomic_load(sb + 2 * NSEG + sc, __ATOMIC_RELAXED, __HIP_MEMORY_SCOPE_AGENT);
            w3 = __hip_atomic_load(sb + 3 * NSEG + sc, __ATOMIC_RELAXED, __HIP_MEMORY_SCOPE_AGENT);
        } while (!__all((int)(w0 >> 32) >= p && (int)(w1 >> 32) >= p &&
                        (int)(w2 >> 32) >= p && (int)(w3 >> 32) >= p));

        float V = __uint_as_float((u32)w0);
        float m = __uint_as_float((u32)w1);
        float h = __uint_as_float((u32)w2);
        float n = __uint_as_float((u32)w3);

        const long long ob = (long long)t0 * NSEG + s;   // used only when owned
        if (ks == KST) {
#pragma unroll
            for (int k = 0; k < KST; ++k) {
                float mc, vp;
                hh_step(V, m, h, n, st[k], le, re, gna, gk, gl, gax, mc, vp);
                if (owned) {
                    const long long o = ob + (long long)k * NSEG;
                    __builtin_nontemporal_store(mc, out_cur + o);
                    __builtin_nontemporal_store(vp, out_volt + o);
                }
            }
        } else {
#pragma unroll 4
            for (int k = 0; k < ks; ++k) {
                float mc, vp;
                hh_step(V, m, h, n, sp[(size_t)k * NSEG], le, re,
                        gna, gk, gl, gax, mc, vp);
                if (owned) {
                    const long long o = ob + (long long)k * NSEG;
                    __builtin_nontemporal_store(mc, out_cur + o);
                    __builtin_nontemporal_store(vp, out_volt + o);
                }
            }
        }

        if (p + 1 < NPHASE) {
            u64* pb = tstate + (size_t)((p + 1) & 1) * 4 * NSEG;
            if (owned) {
                __hip_atomic_store(pb + s,            pack_tag(V, p + 1), __ATOMIC_RELAXED, __HIP_MEMORY_SCOPE_AGENT);
                __hip_atomic_store(pb + NSEG + s,     pack_tag(m, p + 1), __ATOMIC_RELAXED, __HIP_MEMORY_SCOPE_AGENT);
                __hip_atomic_store(pb + 2 * NSEG + s, pack_tag(h, p + 1), __ATOMIC_RELAXED, __HIP_MEMORY_SCOPE_AGENT);
                __hip_atomic_store(pb + 3 * NSEG + s, pack_tag(n, p + 1), __ATOMIC_RELAXED, __HIP_MEMORY_SCOPE_AGENT);
            }
        } else if (owned) {
            tail[s] = V; tail[NSEG + s] = m;
            tail[2 * NSEG + s] = h; tail[3 * NSEG + s] = n;
        }
    }
}

__global__ void hh_init(const float* __restrict__ V0, const float* __restrict__ m0,
                        const float* __restrict__ h0, const float* __restrict__ n0,
                        u64* __restrict__ tstate)
{
    const int i = blockIdx.x * blockDim.x + threadIdx.x;
    if (i < NSEG) {
        // buffer 0 = publication for phase 0, tag 0
        tstate[i]            = pack_tag(V0[i], 0);
        tstate[NSEG + i]     = pack_tag(m0[i], 0);
        tstate[2 * NSEG + i] = pack_tag(h0[i], 0);
        tstate[3 * NSEG + i] = pack_tag(n0[i], 0);
        // buffer 1: stamp invalid tag (replay determinism — clear stale tags)
        u64* b1 = tstate + 4 * NSEG;
        const u64 inv = (u64)(u32)0x80000000u << 32;
        b1[i] = inv; b1[NSEG + i] = inv; b1[2 * NSEG + i] = inv; b1[3 * NSEG + i] = inv;
    }
}

extern "C" void kernel_launch(void* const* d_in, const int* in_sizes, int n_in,
                              void* d_out, int out_size, void* d_ws, size_t ws_size,
                              hipStream_t stream)
{
    const float* stim = (const float*)d_in[0];
    const float* V0   = (const float*)d_in[1];
    const float* m0   = (const float*)d_in[2];
    const float* h0   = (const float*)d_in[3];
    const float* n0   = (const float*)d_in[4];
    const float* gna  = (const float*)d_in[5];
    const float* gk   = (const float*)d_in[6];
    const float* gl   = (const float*)d_in[7];
    const float* gax  = (const float*)d_in[8];

    float* out      = (float*)d_out;
    float* out_cur  = out;
    float* out_volt = out + (size_t)TSTEPS * NSEG;
    float* tail     = out + 2 * (size_t)TSTEPS * NSEG;   // Vf, mf, hf, nf

    u64* tstate = (u64*)d_ws;    // 2 * 4 * NSEG tagged words = 128 KiB

    hipLaunchKernelGGL(hh_init, dim3(8), dim3(256), 0, stream,
                       V0, m0, h0, n0, tstate);
    hipLaunchKernelGGL(hh_persist, dim3(NBLK), dim3(WAVE), 0, stream,
                       stim, gna, gk, gl, gax, tstate,
                       out_cur, out_volt, tail);
}